// Round 2
// baseline (10221.364 us; speedup 1.0000x reference)
//
#include <hip/hip_runtime.h>
#include <hip/hip_bf16.h>

using bf16 = __hip_bfloat16;
typedef __attribute__((ext_vector_type(8))) short short8;
typedef __attribute__((ext_vector_type(4))) float f32x4;

static __device__ __forceinline__ float b2f(short s) {
    unsigned u = ((unsigned)(unsigned short)s) << 16;
    return __builtin_bit_cast(float, u);
}
static __device__ __forceinline__ short f2b(float f) {
    __hip_bfloat16 h = __float2bfloat16(f);
    return __builtin_bit_cast(short, h);
}

// ---------------- f32 -> bf16 conversion (8 elems/thread) ----------------
__global__ void f32_to_bf16_vec(const float* __restrict__ in, bf16* __restrict__ out, int n8) {
    int i = blockIdx.x * blockDim.x + threadIdx.x;
    if (i >= n8) return;
    const f32x4* p = (const f32x4*)(in + (size_t)i * 8);
    f32x4 a = p[0], b = p[1];
    short8 o;
    o[0] = f2b(a[0]); o[1] = f2b(a[1]); o[2] = f2b(a[2]); o[3] = f2b(a[3]);
    o[4] = f2b(b[0]); o[5] = f2b(b[1]); o[6] = f2b(b[2]); o[7] = f2b(b[3]);
    *(short8*)(out + (size_t)i * 8) = o;
}

// ---------------- GEMM: C = act(X @ W^T + bias), bf16 in/out ----------------
template<int K, bool RELU>
__global__ __launch_bounds__(256) void gemm_xwt(
    const bf16* __restrict__ X, const bf16* __restrict__ W,
    const float* __restrict__ bias, bf16* __restrict__ C, int Nout)
{
    __shared__ bf16 As[128][40];
    __shared__ bf16 Bs[128][40];
    const int tid  = threadIdx.x;
    const int wave = tid >> 6, lane = tid & 63;
    const int wr = wave >> 1, wc = wave & 1;
    const long Mbase = (long)blockIdx.x * 128;
    const int  Nbase = blockIdx.y * 128;
    const int kg = (lane >> 4) * 8;

    f32x4 acc[4][4];
#pragma unroll
    for (int i = 0; i < 4; ++i)
#pragma unroll
        for (int j = 0; j < 4; ++j) acc[i][j] = (f32x4){0.f, 0.f, 0.f, 0.f};

    for (int kb = 0; kb < K / 32; ++kb) {
        __syncthreads();
#pragma unroll
        for (int q = 0; q < 2; ++q) {
            int idx = q * 256 + tid;
            int row = idx >> 2, kp = (idx & 3) * 8;
            *(short8*)&As[row][kp] = *(const short8*)&X[(Mbase + row) * K + kb * 32 + kp];
            *(short8*)&Bs[row][kp] = *(const short8*)&W[(long)(Nbase + row) * K + kb * 32 + kp];
        }
        __syncthreads();
        short8 a[4], b[4];
#pragma unroll
        for (int mt = 0; mt < 4; ++mt)
            a[mt] = *(const short8*)&As[wr * 64 + mt * 16 + (lane & 15)][kg];
#pragma unroll
        for (int nt = 0; nt < 4; ++nt)
            b[nt] = *(const short8*)&Bs[wc * 64 + nt * 16 + (lane & 15)][kg];
#pragma unroll
        for (int mt = 0; mt < 4; ++mt)
#pragma unroll
            for (int nt = 0; nt < 4; ++nt)
                acc[mt][nt] = __builtin_amdgcn_mfma_f32_16x16x32_bf16(a[mt], b[nt], acc[mt][nt], 0, 0, 0);
    }

#pragma unroll
    for (int mt = 0; mt < 4; ++mt) {
        int row0 = wr * 64 + mt * 16 + (lane >> 4) * 4;
#pragma unroll
        for (int nt = 0; nt < 4; ++nt) {
            int col = Nbase + wc * 64 + nt * 16 + (lane & 15);
            float bv = bias[col];
#pragma unroll
            for (int r = 0; r < 4; ++r) {
                float v = acc[mt][nt][r] + bv;
                if (RELU) v = fmaxf(v, 0.f);
                C[(Mbase + row0 + r) * (long)Nout + col] = __float2bfloat16(v);
            }
        }
    }
}

// ---------------- LayerNorm rows of 512, bf16 -> bf16 ----------------
__global__ __launch_bounds__(256) void ln_rows512(
    const bf16* __restrict__ in, bf16* __restrict__ out,
    const float* __restrict__ g, const float* __restrict__ be)
{
    const int lane = threadIdx.x & 63;
    const long row = (long)blockIdx.x * 4 + (threadIdx.x >> 6);
    const bf16* rp = in + row * 512;
    short8 v = *(const short8*)&rp[lane * 8];
    float x[8]; float s = 0.f, sq = 0.f;
#pragma unroll
    for (int j = 0; j < 8; ++j) { x[j] = b2f(v[j]); s += x[j]; sq += x[j] * x[j]; }
#pragma unroll
    for (int m = 1; m < 64; m <<= 1) { s += __shfl_xor(s, m); sq += __shfl_xor(sq, m); }
    float mu   = s * (1.f / 512.f);
    float var  = sq * (1.f / 512.f) - mu * mu;
    float rstd = rsqrtf(var + 1e-5f);
    short8 o;
#pragma unroll
    for (int j = 0; j < 8; ++j) {
        int c = lane * 8 + j;
        o[j] = f2b((x[j] - mu) * rstd * g[c] + be[c]);
    }
    *(short8*)(out + row * 512 + lane * 8) = o;
}

// ---------------- final LayerNorm rows of 512, bf16 -> f32 ----------------
__global__ __launch_bounds__(256) void ln_rows512_f32out(
    const bf16* __restrict__ in, float* __restrict__ out,
    const float* __restrict__ g, const float* __restrict__ be)
{
    const int lane = threadIdx.x & 63;
    const long row = (long)blockIdx.x * 4 + (threadIdx.x >> 6);
    const bf16* rp = in + row * 512;
    short8 v = *(const short8*)&rp[lane * 8];
    float x[8]; float s = 0.f, sq = 0.f;
#pragma unroll
    for (int j = 0; j < 8; ++j) { x[j] = b2f(v[j]); s += x[j]; sq += x[j] * x[j]; }
#pragma unroll
    for (int m = 1; m < 64; m <<= 1) { s += __shfl_xor(s, m); sq += __shfl_xor(sq, m); }
    float mu   = s * (1.f / 512.f);
    float var  = sq * (1.f / 512.f) - mu * mu;
    float rstd = rsqrtf(var + 1e-5f);
    float* op = out + row * 512 + lane * 8;
#pragma unroll
    for (int c4 = 0; c4 < 2; ++c4) {
        f32x4 o;
#pragma unroll
        for (int j = 0; j < 4; ++j) {
            int c = lane * 8 + c4 * 4 + j;
            o[j] = (x[c4 * 4 + j] - mu) * rstd * g[c] + be[c];
        }
        *(f32x4*)(op + c4 * 4) = o;
    }
}

// ---------------- 16-block group barrier (device-scope atomics) ----------------
static __device__ __forceinline__ void group_barrier(unsigned* cnt, unsigned target) {
    __threadfence();
    __syncthreads();
    if (threadIdx.x == 0) {
        __hip_atomic_fetch_add(cnt, 1u, __ATOMIC_RELEASE, __HIP_MEMORY_SCOPE_AGENT);
        unsigned v;
        do {
            v = __hip_atomic_load(cnt, __ATOMIC_RELAXED, __HIP_MEMORY_SCOPE_AGENT);
            if (v < target) __builtin_amdgcn_s_sleep(2);
        } while (v < target);
    }
    __syncthreads();
    __threadfence();
}

// ---------------- GRU scan v2: 256 blocks, Whh slice LDS-resident ----------------
// Grid 256 = 16 batch-chunks (g, 32 rows) x 16 col-chunks (32 h-cols).
// Block's Whh slice: rows {g*512? no: gate*512 + c0 + j} -> LDS [96][520] bf16, loaded once.
// h exchanged pre-masked bf16 via double-buffered global (hA/hB); f32 master in regs.
// Group barrier syncs only the 16 blocks sharing a batch-chunk.
__global__ __launch_bounds__(512) void gru_scan2(
    const bf16* __restrict__ gi, const float* __restrict__ on_reset,
    const float* __restrict__ hx, const float* __restrict__ Whh_f32,
    const float* __restrict__ bhh,
    bf16* __restrict__ hA, bf16* __restrict__ hB,
    bf16* __restrict__ h_all, float* __restrict__ hT,
    unsigned* __restrict__ bar)
{
    __shared__ bf16  Wl[96][520];   // row stride 1040B: 16B-aligned, uniform banks
    __shared__ float gh[32][100];   // cross-wave gh exchange

    const int tid = threadIdx.x;
    const int bid = blockIdx.x;
    // XCD-affinity swizzle: the 16 blocks of a group share bid&7 (same XCD if round-robin)
    const int cxcd = bid & 7;
    const int kk   = bid >> 3;            // 0..31
    const int g    = (cxcd << 1) | (kk >> 4);  // batch-chunk 0..15
    const int cchunk = kk & 15;           // col-chunk 0..15
    const int n0 = g * 32, c0 = cchunk * 32;
    unsigned* cnt = bar + g * 32;         // 128B apart per group

    const int wave = tid >> 6, lane = tid & 63;
    const int wr = wave & 1, wc = wave >> 1;   // wr<2 row-tiles, wc<4 (wc==3 idle in MFMA)
    const int lcol = lane & 15, kg = lane >> 4;

    // gate-phase ownership: thread -> (row, 2 cols)
    const int grow = tid >> 4;            // 0..31
    const int gj   = (tid & 15) * 2;      // 0..30

    // ---- load Whh slice into LDS (f32 -> bf16), rows packed [r(32) z(32) n(32)] ----
    for (int i = tid; i < 96 * 128; i += 512) {
        int r  = i >> 7;
        int cc = (i & 127) << 2;
        int growW = (r >> 5) * 512 + c0 + (r & 31);
        f32x4 v = *(const f32x4*)&Whh_f32[(long)growW * 512 + cc];
        Wl[r][cc]     = __float2bfloat16(v[0]);
        Wl[r][cc + 1] = __float2bfloat16(v[1]);
        Wl[r][cc + 2] = __float2bfloat16(v[2]);
        Wl[r][cc + 3] = __float2bfloat16(v[3]);
    }

    // ---- init h master (f32 regs) + write pre-masked h0 to hA ----
    float hf0 = hx[(n0 + grow) * 512 + c0 + gj];
    float hf1 = hx[(n0 + grow) * 512 + c0 + gj + 1];
    {
        float m0 = on_reset[n0 + grow];
        unsigned pk = (unsigned)(unsigned short)f2b(hf0 * m0)
                    | ((unsigned)(unsigned short)f2b(hf1 * m0) << 16);
        *(unsigned*)&hA[(long)(n0 + grow) * 512 + c0 + gj] = pk;
    }
    // hoist bhh for owned cols
    const float bhr0 = bhh[c0 + gj],        bhr1 = bhh[c0 + gj + 1];
    const float bhz0 = bhh[512 + c0 + gj],  bhz1 = bhh[512 + c0 + gj + 1];
    const float bhn0 = bhh[1024 + c0 + gj], bhn1 = bhh[1024 + c0 + gj + 1];

    group_barrier(cnt, 16u);   // Wl is block-local (syncthreads inside covers it); hA visible

    for (int t = 0; t < 128; ++t) {
        const bf16* hcur = (t & 1) ? hB : hA;
        bf16*       hnxt = (t & 1) ? hA : hB;

        // prefetch gi (2 cols x 3 gates) + masks — independent of h
        const bf16* girow = gi + ((long)t * 512 + n0 + grow) * 1536;
        unsigned gir = *(const unsigned*)&girow[c0 + gj];
        unsigned giz = *(const unsigned*)&girow[512 + c0 + gj];
        unsigned gin = *(const unsigned*)&girow[1024 + c0 + gj];
        float mt = on_reset[(long)t * 512 + n0 + grow];
        float mnext = (t < 127) ? on_reset[(long)(t + 1) * 512 + n0 + grow] : 0.f;

        // ---- gh = (h*m) @ Whh_slice^T : C[32 rows x 96 cols], K=512 ----
        if (wc < 3) {
            short8 af[16];
            const bf16* arow = hcur + (long)(n0 + wr * 16 + lcol) * 512;
#pragma unroll
            for (int kc = 0; kc < 16; ++kc)
                af[kc] = *(const short8*)&arow[kc * 32 + kg * 8];
            f32x4 acc0 = (f32x4){0.f, 0.f, 0.f, 0.f};
            f32x4 acc1 = (f32x4){0.f, 0.f, 0.f, 0.f};
#pragma unroll
            for (int kc = 0; kc < 16; ++kc) {
                short8 b0 = *(const short8*)&Wl[wc * 32 + lcol][kc * 32 + kg * 8];
                acc0 = __builtin_amdgcn_mfma_f32_16x16x32_bf16(af[kc], b0, acc0, 0, 0, 0);
            }
#pragma unroll
            for (int kc = 0; kc < 16; ++kc) {
                short8 b1 = *(const short8*)&Wl[wc * 32 + 16 + lcol][kc * 32 + kg * 8];
                acc1 = __builtin_amdgcn_mfma_f32_16x16x32_bf16(af[kc], b1, acc1, 0, 0, 0);
            }
#pragma unroll
            for (int r = 0; r < 4; ++r) {
                gh[wr * 16 + kg * 4 + r][wc * 32 + lcol]      = acc0[r];
                gh[wr * 16 + kg * 4 + r][wc * 32 + 16 + lcol] = acc1[r];
            }
        }
        __syncthreads();

        // ---- gates + h update (2 elems/thread) ----
        float ir0 = b2f((short)(gir & 0xffff)), ir1 = b2f((short)(gir >> 16));
        float iz0 = b2f((short)(giz & 0xffff)), iz1 = b2f((short)(giz >> 16));
        float in0 = b2f((short)(gin & 0xffff)), in1 = b2f((short)(gin >> 16));
        {
            float hrv = gh[grow][gj] + bhr0;
            float hzv = gh[grow][32 + gj] + bhz0;
            float hnv = gh[grow][64 + gj] + bhn0;
            float rr = 1.f / (1.f + __expf(-(ir0 + hrv)));
            float zz = 1.f / (1.f + __expf(-(iz0 + hzv)));
            float nn = tanhf(in0 + rr * hnv);
            hf0 = (1.f - zz) * nn + zz * (hf0 * mt);
        }
        {
            float hrv = gh[grow][gj + 1] + bhr1;
            float hzv = gh[grow][32 + gj + 1] + bhz1;
            float hnv = gh[grow][64 + gj + 1] + bhn1;
            float rr = 1.f / (1.f + __expf(-(ir1 + hrv)));
            float zz = 1.f / (1.f + __expf(-(iz1 + hzv)));
            float nn = tanhf(in1 + rr * hnv);
            hf1 = (1.f - zz) * nn + zz * (hf1 * mt);
        }

        // h_all (unmasked, for final LN) + hnxt (pre-masked with m_{t+1})
        {
            unsigned pk = (unsigned)(unsigned short)f2b(hf0)
                        | ((unsigned)(unsigned short)f2b(hf1) << 16);
            *(unsigned*)&h_all[((long)t * 512 + n0 + grow) * 512 + c0 + gj] = pk;
        }
        if (t < 127) {
            unsigned pk = (unsigned)(unsigned short)f2b(hf0 * mnext)
                        | ((unsigned)(unsigned short)f2b(hf1 * mnext) << 16);
            *(unsigned*)&hnxt[(long)(n0 + grow) * 512 + c0 + gj] = pk;
        }

        group_barrier(cnt, 16u * (unsigned)(t + 2));
    }

    // hT = h_127 (unmasked, f32)
    hT[(n0 + grow) * 512 + c0 + gj]     = hf0;
    hT[(n0 + grow) * 512 + c0 + gj + 1] = hf1;
}

// ---------------- launch ----------------
extern "C" void kernel_launch(void* const* d_in, const int* in_sizes, int n_in,
                              void* d_out, int out_size, void* d_ws, size_t ws_size,
                              hipStream_t stream) {
    const float* obs      = (const float*)d_in[0];
    const float* hx       = (const float*)d_in[1];
    const float* on_reset = (const float*)d_in[2];
    const float* W1  = (const float*)d_in[3];
    const float* b1  = (const float*)d_in[4];
    const float* g1  = (const float*)d_in[5];
    const float* be1 = (const float*)d_in[6];
    const float* W2  = (const float*)d_in[7];
    const float* b2  = (const float*)d_in[8];
    const float* g2  = (const float*)d_in[9];
    const float* be2 = (const float*)d_in[10];
    const float* Wih = (const float*)d_in[11];
    const float* Whh = (const float*)d_in[12];
    const float* bih = (const float*)d_in[13];
    const float* bhh = (const float*)d_in[14];
    const float* gr  = (const float*)d_in[15];
    const float* br  = (const float*)d_in[16];

    // workspace layout (bytes) — total 272,236,544 (same as proven R1 footprint)
    char* ws = (char*)d_ws;
    bf16* W1b  = (bf16*)(ws + 0);                    //   131072
    bf16* W2b  = (bf16*)(ws + 131072);               //   524288
    bf16* Wihb = (bf16*)(ws + 655360);               //  1572864
    bf16* hAb  = (bf16*)(ws + 2228224);              //   524288 (was Whhb)
    bf16* hBb  = (bf16*)(ws + 2752512);              //   524288... fits below 3801088? 2752512+524288=3276800 ok
    unsigned* bar = (unsigned*)(ws + 3276800);       //     2048 (3276800+2048 <= 3801088)
    bf16* Y    = (bf16*)(ws + 3801088);              // 67108864  (post-LN acts; later h_all)
    bf16* GI   = (bf16*)(ws + 3801088 + 67108864);   // 201326592
    bf16* X1   = GI;                                 // alias: pre-LN acts
    bf16* OBSB = (bf16*)((char*)GI + 67108864);      // alias: obs bf16
    bf16* h_all = Y;                                 // alias: Y dead after gi GEMM

    // conversions
    f32_to_bf16_vec<<<(1048576 + 255) / 256, 256, 0, stream>>>(obs, OBSB, 1048576);
    f32_to_bf16_vec<<<(8192 + 255) / 256,  256, 0, stream>>>(W1,  W1b,  8192);
    f32_to_bf16_vec<<<(32768 + 255) / 256, 256, 0, stream>>>(W2,  W2b,  32768);
    f32_to_bf16_vec<<<(98304 + 255) / 256, 256, 0, stream>>>(Wih, Wihb, 98304);

    // MLP + gi
    gemm_xwt<128, true><<<dim3(512, 4), 256, 0, stream>>>(OBSB, W1b, b1, X1, 512);
    ln_rows512<<<16384, 256, 0, stream>>>(X1, Y, g1, be1);
    gemm_xwt<512, true><<<dim3(512, 4), 256, 0, stream>>>(Y, W2b, b2, X1, 512);
    ln_rows512<<<16384, 256, 0, stream>>>(X1, Y, g2, be2);
    gemm_xwt<512, false><<<dim3(512, 12), 256, 0, stream>>>(Y, Wihb, bih, GI, 1536);

    // scan
    hipMemsetAsync(bar, 0, 2048, stream);
    float* out_p = (float*)d_out;
    float* hT_p  = out_p + (size_t)65536 * 512;
    gru_scan2<<<256, 512, 0, stream>>>(GI, on_reset, hx, Whh, bhh,
                                       hAb, hBb, h_all, hT_p, bar);

    // final LN: bf16 h_all -> f32 out
    ln_rows512_f32out<<<16384, 256, 0, stream>>>(h_all, out_p, gr, br);
}